// Round 3
// baseline (411.683 us; speedup 1.0000x reference)
//
#include <hip/hip_runtime.h>
#include <stdint.h>

// ---------------------------------------------------------------------------
// Fused causal MHA: qkv = x @ w_qkv^T ; flash-attn ; out = y @ w_out^T + b
// B=2, T=2048, C=1024, H=16, Dh=64.  bf16 MFMA compute, fp32 accumulate.
// ---------------------------------------------------------------------------

typedef __bf16 bf16x8 __attribute__((ext_vector_type(8)));
typedef float  f32x4  __attribute__((ext_vector_type(4)));

#define MFMA_16x16x32(a, b, c) __builtin_amdgcn_mfma_f32_16x16x32_bf16((a), (b), (c), 0, 0, 0)

__device__ __forceinline__ unsigned short f2bf(float f) {
    union { float f; unsigned int u; } c;
    c.f = f;
    unsigned int u = c.u;
    return (unsigned short)((u + 0x7fffu + ((u >> 16) & 1u)) >> 16);  // RNE
}

// 16-lane-group butterfly helpers via ds_swizzle (BitMode: offset=(xor<<10)|0x1F)
__device__ __forceinline__ float swz_max(float v, const int imm_unused) { return v; }
#define SWZ_F(v, imm) __int_as_float(__builtin_amdgcn_ds_swizzle(__float_as_int(v), (imm)))

// ---------------- fp32 -> bf16 conversion (3 sources, 1 launch) ----------------
__global__ __launch_bounds__(256) void cvt3_kernel(const float* __restrict__ a,
                                                   const float* __restrict__ b,
                                                   const float* __restrict__ c,
                                                   unsigned short* __restrict__ out,
                                                   int na4, int nb4, int ntot4) {
    int i = blockIdx.x * 256 + threadIdx.x;
    const int stride = gridDim.x * 256;
    for (; i < ntot4; i += stride) {
        const float4* src;
        int j;
        if (i < na4)            { src = (const float4*)a; j = i; }
        else if (i < na4 + nb4) { src = (const float4*)b; j = i - na4; }
        else                    { src = (const float4*)c; j = i - na4 - nb4; }
        float4 v = src[j];
        ushort4 o;
        o.x = f2bf(v.x); o.y = f2bf(v.y); o.z = f2bf(v.z); o.w = f2bf(v.w);
        reinterpret_cast<ushort4*>(out)[i] = o;
    }
}

// ---------------- async global -> LDS, 16B per lane ----------------
__device__ __forceinline__ void gload_lds16(const void* g, void* l) {
    __builtin_amdgcn_global_load_lds((const __attribute__((address_space(1))) void*)g,
                                     (__attribute__((address_space(3))) void*)l,
                                     16, 0, 0);
}

// ---------------- shared GEMM core: C(128x128) = A(MxK) * B(NxK)^T ----------
__device__ __forceinline__ void gemm_core_128(const unsigned short* __restrict__ A,
                                              const unsigned short* __restrict__ B,
                                              int K, int tM, int tN,
                                              unsigned short* As, unsigned short* Bs,
                                              f32x4 acc[4][4]) {
    const int tid  = threadIdx.x;
    const int lane = tid & 63;
    const int w    = tid >> 6;
    const int wr   = w >> 1, wc = w & 1;
    const int lr   = lane & 15, lg = lane >> 4;

    const int o0 = tid * 16;
    const int o1 = o0 + 4096;
    const int row0 = o0 >> 6, cb0 = o0 & 63;
    const int row1 = o1 >> 6, cb1 = o1 & 63;

    const char* Ab = (const char*)A;
    const char* Bb = (const char*)B;
    const size_t rstride = (size_t)K * 2;

    for (int kt = 0; kt < K; kt += 32) {
        const size_t kbyte = (size_t)kt * 2;
        gload_lds16(Ab + (size_t)(tM + row0) * rstride + kbyte + cb0, (char*)As + o0);
        gload_lds16(Ab + (size_t)(tM + row1) * rstride + kbyte + cb1, (char*)As + o1);
        gload_lds16(Bb + (size_t)(tN + row0) * rstride + kbyte + cb0, (char*)Bs + o0);
        gload_lds16(Bb + (size_t)(tN + row1) * rstride + kbyte + cb1, (char*)Bs + o1);
        __syncthreads();

        bf16x8 a[4], b[4];
#pragma unroll
        for (int m = 0; m < 4; ++m)
            a[m] = *reinterpret_cast<const bf16x8*>(As + (wr * 64 + m * 16 + lr) * 32 + lg * 8);
#pragma unroll
        for (int n = 0; n < 4; ++n)
            b[n] = *reinterpret_cast<const bf16x8*>(Bs + (wc * 64 + n * 16 + lr) * 32 + lg * 8);
#pragma unroll
        for (int m = 0; m < 4; ++m)
#pragma unroll
            for (int n = 0; n < 4; ++n)
                acc[m][n] = MFMA_16x16x32(a[m], b[n], acc[m][n]);
        __syncthreads();
    }
}

// ---------------- GEMM1: qkv projection, scatter epilogue ----------------
__global__ __launch_bounds__(256) void gemm_qkv_kernel(const unsigned short* __restrict__ Xb,
                                                       const unsigned short* __restrict__ Wb,
                                                       unsigned short* __restrict__ Qo,
                                                       unsigned short* __restrict__ Ko,
                                                       unsigned short* __restrict__ Vt) {
    __shared__ __align__(16) unsigned short As[128 * 32];
    __shared__ __align__(16) unsigned short Bs[128 * 32];
    f32x4 acc[4][4];
#pragma unroll
    for (int m = 0; m < 4; ++m)
#pragma unroll
        for (int n = 0; n < 4; ++n)
#pragma unroll
            for (int r = 0; r < 4; ++r) acc[m][n][r] = 0.0f;

    const int tM = blockIdx.y * 128, tN = blockIdx.x * 128;
    gemm_core_128(Xb, Wb, 1024, tM, tN, As, Bs, acc);

    const int lane = threadIdx.x & 63, w = threadIdx.x >> 6;
    const int wr = w >> 1, wc = w & 1, lr = lane & 15, lg = lane >> 4;
#pragma unroll
    for (int m = 0; m < 4; ++m)
#pragma unroll
        for (int n = 0; n < 4; ++n)
#pragma unroll
            for (int r = 0; r < 4; ++r) {
                const int gr = tM + wr * 64 + m * 16 + 4 * lg + r;
                const int gc = tN + wc * 64 + n * 16 + lr;
                const float v = acc[m][n][r];
                const int bb = gr >> 11, t = gr & 2047;
                const int kind = gc >> 10, c = gc & 1023;
                const int h = c >> 6, d = c & 63;
                const int bh = bb * 16 + h;
                if (kind == 0)      Qo[((size_t)bh * 2048 + t) * 64 + d] = f2bf(v * 0.125f);
                else if (kind == 1) Ko[((size_t)bh * 2048 + t) * 64 + d] = f2bf(v);
                else                Vt[((size_t)bh * 64 + d) * 2048 + t] = f2bf(v);
            }
}

// ---------------- GEMM2: output projection + bias ----------------
__global__ __launch_bounds__(256) void gemm_out_kernel(const unsigned short* __restrict__ Yb,
                                                       const unsigned short* __restrict__ Wob,
                                                       const float* __restrict__ bias,
                                                       float* __restrict__ out) {
    __shared__ __align__(16) unsigned short As[128 * 32];
    __shared__ __align__(16) unsigned short Bs[128 * 32];
    f32x4 acc[4][4];
#pragma unroll
    for (int m = 0; m < 4; ++m)
#pragma unroll
        for (int n = 0; n < 4; ++n)
#pragma unroll
            for (int r = 0; r < 4; ++r) acc[m][n][r] = 0.0f;

    const int tM = blockIdx.y * 128, tN = blockIdx.x * 128;
    gemm_core_128(Yb, Wob, 1024, tM, tN, As, Bs, acc);

    const int lane = threadIdx.x & 63, w = threadIdx.x >> 6;
    const int wr = w >> 1, wc = w & 1, lr = lane & 15, lg = lane >> 4;
#pragma unroll
    for (int m = 0; m < 4; ++m)
#pragma unroll
        for (int n = 0; n < 4; ++n)
#pragma unroll
            for (int r = 0; r < 4; ++r) {
                const int gr = tM + wr * 64 + m * 16 + 4 * lg + r;
                const int gc = tN + wc * 64 + n * 16 + lr;
                out[(size_t)gr * 1024 + gc] = acc[m][n][r] + bias[gc];
            }
}

// ---------------- flash attention (causal, online softmax) ----------------
// 1024 blocks x 256 thr; 4 waves/block, 16 q-rows/wave, KVBLK=64.
// 16 waves/CU (4/SIMD) for latency hiding.  bh packed per XCD (bid&7) so each
// XCD's L2 holds only 4 heads' K/V (2 MB).  Bit-reversed q-chunk rank spreads
// long/short waves across CUs.  P round-trip via XOR-swizzled per-wave LDS.
__global__ __launch_bounds__(256, 4) void attn_kernel(const unsigned short* __restrict__ Q,
                                                      const unsigned short* __restrict__ Kb,
                                                      const unsigned short* __restrict__ Vt,
                                                      unsigned short* __restrict__ Y) {
    __shared__ __align__(16) unsigned short P_lds[4][16 * 64];  // 2 KB/wave, swizzled
    const int tid = threadIdx.x, lane = tid & 63, w = tid >> 6;
    const int lr = lane & 15, lg = lane >> 4;

    const int bid  = blockIdx.x;
    const int s    = bid >> 3;
    const int bh   = (bid & 7) * 4 + (s & 3);          // 4 heads per XCD
    const int rank = s >> 2;                            // [0,32)
    const int qc   = ((rank & 1) << 4) | ((rank & 2) << 2) | (rank & 4)
                   | ((rank & 8) >> 2) | ((rank & 16) >> 4);   // bitrev5
    const int qw   = qc * 64 + w * 16;                  // first q row of wave

    const unsigned short* Qh = Q  + (size_t)bh * 2048 * 64;
    const unsigned short* Kh = Kb + (size_t)bh * 2048 * 64;
    const unsigned short* Vh = Vt + (size_t)bh * 64 * 2048;
    char* Pw = (char*)&P_lds[w][0];

    // Q fragments (rows qw..qw+15): A-frag row=lr, k = kk*32 + lg*8 + j
    bf16x8 aq[2];
#pragma unroll
    for (int kk = 0; kk < 2; ++kk)
        aq[kk] = *reinterpret_cast<const bf16x8*>(Qh + (size_t)(qw + lr) * 64 + kk * 32 + lg * 8);

    f32x4 o[4];                 // o[nd]: row=4lg+r, col d = nd*16+lr
    float mrun[4], lrun[4];
#pragma unroll
    for (int nd = 0; nd < 4; ++nd)
#pragma unroll
        for (int r = 0; r < 4; ++r) o[nd][r] = 0.0f;
#pragma unroll
    for (int r = 0; r < 4; ++r) { mrun[r] = -INFINITY; lrun[r] = 0.0f; }

    const int last = qw + 15;
    for (int kb = 0; kb <= last; kb += 64) {
        const int rem = last - kb;
        int nt = (rem >> 4) + 1; if (nt > 4) nt = 4;    // active 16-wide kv tiles

        // ---- S = Q K^T ----
        f32x4 sv[4];
#pragma unroll
        for (int n = 0; n < 4; ++n)
#pragma unroll
            for (int r = 0; r < 4; ++r) sv[n][r] = 0.0f;

        bf16x8 bk[4][2];
#pragma unroll
        for (int n = 0; n < 4; ++n)
            if (n < nt)
#pragma unroll
                for (int kk = 0; kk < 2; ++kk)
                    bk[n][kk] = *reinterpret_cast<const bf16x8*>(
                        Kh + (size_t)(kb + n * 16 + lr) * 64 + kk * 32 + lg * 8);
#pragma unroll
        for (int n = 0; n < 4; ++n)
            if (n < nt)
#pragma unroll
                for (int kk = 0; kk < 2; ++kk)
                    sv[n] = MFMA_16x16x32(aq[kk], bk[n][kk], sv[n]);

        // ---- issue V loads early (hide under softmax) ----
        bf16x8 bv[4][2];
#pragma unroll
        for (int nd = 0; nd < 4; ++nd)
#pragma unroll
            for (int kk = 0; kk < 2; ++kk)
                bv[nd][kk] = *reinterpret_cast<const bf16x8*>(
                    Vh + (size_t)(nd * 16 + lr) * 2048 + kb + kk * 32 + lg * 8);

        // ---- causal mask (final iteration only); also forces n>=nt to -inf ----
        if (kb + 64 > qw) {
#pragma unroll
            for (int n = 0; n < 4; ++n)
#pragma unroll
                for (int r = 0; r < 4; ++r)
                    if (kb + n * 16 + lr > qw + 4 * lg + r) sv[n][r] = -INFINITY;
        }

        // ---- online softmax (rows 4lg+r; reduce across 16-lane group) ----
        float al[4];
#pragma unroll
        for (int r = 0; r < 4; ++r) {
            float v = fmaxf(fmaxf(sv[0][r], sv[1][r]), fmaxf(sv[2][r], sv[3][r]));
            v = fmaxf(v, SWZ_F(v, 0x041F));
            v = fmaxf(v, SWZ_F(v, 0x081F));
            v = fmaxf(v, SWZ_F(v, 0x101F));
            v = fmaxf(v, SWZ_F(v, 0x201F));
            const float mn = fmaxf(mrun[r], v);
            al[r] = __expf(mrun[r] - mn);
            mrun[r] = mn;
        }
#pragma unroll
        for (int n = 0; n < 4; ++n)
#pragma unroll
            for (int r = 0; r < 4; ++r)
                sv[n][r] = __expf(sv[n][r] - mrun[r]);   // -inf -> 0
#pragma unroll
        for (int r = 0; r < 4; ++r) {
            float v = (sv[0][r] + sv[1][r]) + (sv[2][r] + sv[3][r]);
            v += SWZ_F(v, 0x041F);
            v += SWZ_F(v, 0x081F);
            v += SWZ_F(v, 0x101F);
            v += SWZ_F(v, 0x201F);
            lrun[r] = lrun[r] * al[r] + v;
        }

        // ---- rescale O ----
#pragma unroll
        for (int nd = 0; nd < 4; ++nd)
#pragma unroll
            for (int r = 0; r < 4; ++r) o[nd][r] *= al[r];

        // ---- P -> LDS (bf16, XOR-swizzled rows) ----
#pragma unroll
        for (int n = 0; n < 4; ++n)
#pragma unroll
            for (int r = 0; r < 4; ++r) {
                const int row = 4 * lg + r;
                const int byte = (row * 128 + (n * 16 + lr) * 2) ^ ((row & 7) << 4);
                *(unsigned short*)(Pw + byte) = f2bf(sv[n][r]);
            }

        // ---- O += P V ----
        bf16x8 ap[2];
#pragma unroll
        for (int kk = 0; kk < 2; ++kk) {
            const int base = (lr * 128 + kk * 64 + lg * 16) ^ ((lr & 7) << 4);
            ap[kk] = *reinterpret_cast<const bf16x8*>(Pw + base);
        }
#pragma unroll
        for (int nd = 0; nd < 4; ++nd)
#pragma unroll
            for (int kk = 0; kk < 2; ++kk)
                o[nd] = MFMA_16x16x32(ap[kk], bv[nd][kk], o[nd]);
    }

    // ---- epilogue: y = O / l -> (b, t, h*64+d) bf16 ----
    const int b = bh >> 4, h = bh & 15;
#pragma unroll
    for (int r = 0; r < 4; ++r) {
        const float inv = 1.0f / lrun[r];
        const int t = qw + 4 * lg + r;
#pragma unroll
        for (int nd = 0; nd < 4; ++nd) {
            const int d = nd * 16 + lr;
            Y[((size_t)(b * 2048 + t)) * 1024 + h * 64 + d] = f2bf(o[nd][r] * inv);
        }
    }
}

// ---------------------------------------------------------------------------
extern "C" void kernel_launch(void* const* d_in, const int* in_sizes, int n_in,
                              void* d_out, int out_size, void* d_ws, size_t ws_size,
                              hipStream_t stream) {
    (void)in_sizes; (void)n_in; (void)out_size; (void)ws_size;
    const float* x     = (const float*)d_in[0];
    const float* w_qkv = (const float*)d_in[1];
    const float* w_out = (const float*)d_in[2];
    const float* b_out = (const float*)d_in[3];
    float* out = (float*)d_out;

    // Workspace (bf16 elems), 41 MiB total. Yb aliases xb (x dead after GEMM1).
    unsigned short* xb    = (unsigned short*)d_ws;                    // 4096x1024
    unsigned short* Yb    = xb;                                       // alias
    unsigned short* wqkvb = xb    + (size_t)4096 * 1024;              // 3072x1024
    unsigned short* woutb = wqkvb + (size_t)3072 * 1024;              // 1024x1024
    unsigned short* Qb    = woutb + (size_t)1024 * 1024;              // 32x2048x64
    unsigned short* Kbuf  = Qb    + (size_t)32 * 2048 * 64;           // 32x2048x64
    unsigned short* Vt    = Kbuf  + (size_t)32 * 2048 * 64;           // 32x64x2048

    const int na4 = 4096 * 1024 / 4, nb4 = 3072 * 1024 / 4, nc4 = 1024 * 1024 / 4;
    cvt3_kernel<<<2048, 256, 0, stream>>>(x, w_qkv, w_out, xb, na4, nb4, na4 + nb4 + nc4);
    gemm_qkv_kernel<<<dim3(24, 32), 256, 0, stream>>>(xb, wqkvb, Qb, Kbuf, Vt);
    attn_kernel<<<1024, 256, 0, stream>>>(Qb, Kbuf, Vt, Yb);
    gemm_out_kernel<<<dim3(8, 32), 256, 0, stream>>>(Yb, woutb, b_out, out);
}

// Round 6
// 262.809 us; speedup vs baseline: 1.5665x; 1.5665x over previous
//
#include <hip/hip_runtime.h>
#include <stdint.h>

// ---------------------------------------------------------------------------
// Fused causal MHA: qkv = x @ w_qkv^T ; flash-attn ; out = y @ w_out^T + b
// B=2, T=2048, C=1024, H=16, Dh=64.  bf16 MFMA compute, fp32 accumulate.
// Attention: swapped-QK^T 32x32 structure — softmax lane-local, zero LDS,
// zero barriers.  This round: P-redistribution via verified primitives only
// (f2bf pack + __shfl_xor lane^32 exchange); permlane/cvt_pk deferred.
// ---------------------------------------------------------------------------

typedef __bf16 bf16x8 __attribute__((ext_vector_type(8)));
typedef float  f32x4  __attribute__((ext_vector_type(4)));
typedef float  f32x16 __attribute__((ext_vector_type(16)));

#define MFMA16(a, b, c) __builtin_amdgcn_mfma_f32_16x16x32_bf16((a), (b), (c), 0, 0, 0)
#define MFMA32(a, b, c) __builtin_amdgcn_mfma_f32_32x32x16_bf16((a), (b), (c), 0, 0, 0)

__device__ __forceinline__ unsigned short f2bf(float f) {
    union { float f; unsigned int u; } c;
    c.f = f;
    unsigned int u = c.u;
    return (unsigned short)((u + 0x7fffu + ((u >> 16) & 1u)) >> 16);  // RNE
}

// bit-exact bf16 pair pack: lo -> bits[15:0], hi -> bits[31:16]
__device__ __forceinline__ unsigned pack2(float lo, float hi) {
    return ((unsigned)f2bf(hi) << 16) | (unsigned)f2bf(lo);
}

// ---------------- fp32 -> bf16 conversion (3 sources, 1 launch) ----------------
__global__ __launch_bounds__(256) void cvt3_kernel(const float* __restrict__ a,
                                                   const float* __restrict__ b,
                                                   const float* __restrict__ c,
                                                   unsigned short* __restrict__ out,
                                                   int na4, int nb4, int ntot4) {
    int i = blockIdx.x * 256 + threadIdx.x;
    const int stride = gridDim.x * 256;
    for (; i < ntot4; i += stride) {
        const float4* src;
        int j;
        if (i < na4)            { src = (const float4*)a; j = i; }
        else if (i < na4 + nb4) { src = (const float4*)b; j = i - na4; }
        else                    { src = (const float4*)c; j = i - na4 - nb4; }
        float4 v = src[j];
        ushort4 o;
        o.x = f2bf(v.x); o.y = f2bf(v.y); o.z = f2bf(v.z); o.w = f2bf(v.w);
        reinterpret_cast<ushort4*>(out)[i] = o;
    }
}

// ---------------- async global -> LDS, 16B per lane ----------------
__device__ __forceinline__ void gload_lds16(const void* g, void* l) {
    __builtin_amdgcn_global_load_lds((const __attribute__((address_space(1))) void*)g,
                                     (__attribute__((address_space(3))) void*)l,
                                     16, 0, 0);
}

// ---------------- shared GEMM core: C(128x128) = A(MxK) * B(NxK)^T ----------
__device__ __forceinline__ void gemm_core_128(const unsigned short* __restrict__ A,
                                              const unsigned short* __restrict__ B,
                                              int K, int tM, int tN,
                                              unsigned short* As, unsigned short* Bs,
                                              f32x4 acc[4][4]) {
    const int tid  = threadIdx.x;
    const int lane = tid & 63;
    const int w    = tid >> 6;
    const int wr   = w >> 1, wc = w & 1;
    const int lr   = lane & 15, lg = lane >> 4;

    const int o0 = tid * 16;
    const int o1 = o0 + 4096;
    const int row0 = o0 >> 6, cb0 = o0 & 63;
    const int row1 = o1 >> 6, cb1 = o1 & 63;

    const char* Ab = (const char*)A;
    const char* Bb = (const char*)B;
    const size_t rstride = (size_t)K * 2;

    for (int kt = 0; kt < K; kt += 32) {
        const size_t kbyte = (size_t)kt * 2;
        gload_lds16(Ab + (size_t)(tM + row0) * rstride + kbyte + cb0, (char*)As + o0);
        gload_lds16(Ab + (size_t)(tM + row1) * rstride + kbyte + cb1, (char*)As + o1);
        gload_lds16(Bb + (size_t)(tN + row0) * rstride + kbyte + cb0, (char*)Bs + o0);
        gload_lds16(Bb + (size_t)(tN + row1) * rstride + kbyte + cb1, (char*)Bs + o1);
        __syncthreads();

        bf16x8 a[4], b[4];
#pragma unroll
        for (int m = 0; m < 4; ++m)
            a[m] = *reinterpret_cast<const bf16x8*>(As + (wr * 64 + m * 16 + lr) * 32 + lg * 8);
#pragma unroll
        for (int n = 0; n < 4; ++n)
            b[n] = *reinterpret_cast<const bf16x8*>(Bs + (wc * 64 + n * 16 + lr) * 32 + lg * 8);
#pragma unroll
        for (int m = 0; m < 4; ++m)
#pragma unroll
            for (int n = 0; n < 4; ++n)
                acc[m][n] = MFMA16(a[m], b[n], acc[m][n]);
        __syncthreads();
    }
}

// ---------------- GEMM1: qkv projection, scatter epilogue ----------------
__global__ __launch_bounds__(256) void gemm_qkv_kernel(const unsigned short* __restrict__ Xb,
                                                       const unsigned short* __restrict__ Wb,
                                                       unsigned short* __restrict__ Qo,
                                                       unsigned short* __restrict__ Ko,
                                                       unsigned short* __restrict__ Vt) {
    __shared__ __align__(16) unsigned short As[128 * 32];
    __shared__ __align__(16) unsigned short Bs[128 * 32];
    f32x4 acc[4][4];
#pragma unroll
    for (int m = 0; m < 4; ++m)
#pragma unroll
        for (int n = 0; n < 4; ++n)
#pragma unroll
            for (int r = 0; r < 4; ++r) acc[m][n][r] = 0.0f;

    const int tM = blockIdx.y * 128, tN = blockIdx.x * 128;
    gemm_core_128(Xb, Wb, 1024, tM, tN, As, Bs, acc);

    const int lane = threadIdx.x & 63, w = threadIdx.x >> 6;
    const int wr = w >> 1, wc = w & 1, lr = lane & 15, lg = lane >> 4;
#pragma unroll
    for (int m = 0; m < 4; ++m)
#pragma unroll
        for (int n = 0; n < 4; ++n)
#pragma unroll
            for (int r = 0; r < 4; ++r) {
                const int gr = tM + wr * 64 + m * 16 + 4 * lg + r;
                const int gc = tN + wc * 64 + n * 16 + lr;
                const float v = acc[m][n][r];
                const int bb = gr >> 11, t = gr & 2047;
                const int kind = gc >> 10, c = gc & 1023;
                const int h = c >> 6, d = c & 63;
                const int bh = bb * 16 + h;
                if (kind == 0)      Qo[((size_t)bh * 2048 + t) * 64 + d] = f2bf(v * 0.125f);
                else if (kind == 1) Ko[((size_t)bh * 2048 + t) * 64 + d] = f2bf(v);
                else                Vt[((size_t)bh * 64 + d) * 2048 + t] = f2bf(v);
            }
}

// ---------------- GEMM2: output projection + bias ----------------
__global__ __launch_bounds__(256) void gemm_out_kernel(const unsigned short* __restrict__ Yb,
                                                       const unsigned short* __restrict__ Wob,
                                                       const float* __restrict__ bias,
                                                       float* __restrict__ out) {
    __shared__ __align__(16) unsigned short As[128 * 32];
    __shared__ __align__(16) unsigned short Bs[128 * 32];
    f32x4 acc[4][4];
#pragma unroll
    for (int m = 0; m < 4; ++m)
#pragma unroll
        for (int n = 0; n < 4; ++n)
#pragma unroll
            for (int r = 0; r < 4; ++r) acc[m][n][r] = 0.0f;

    const int tM = blockIdx.y * 128, tN = blockIdx.x * 128;
    gemm_core_128(Yb, Wob, 1024, tM, tN, As, Bs, acc);

    const int lane = threadIdx.x & 63, w = threadIdx.x >> 6;
    const int wr = w >> 1, wc = w & 1, lr = lane & 15, lg = lane >> 4;
#pragma unroll
    for (int m = 0; m < 4; ++m)
#pragma unroll
        for (int n = 0; n < 4; ++n)
#pragma unroll
            for (int r = 0; r < 4; ++r) {
                const int gr = tM + wr * 64 + m * 16 + 4 * lg + r;
                const int gc = tN + wc * 64 + n * 16 + lr;
                out[(size_t)gr * 1024 + gc] = acc[m][n][r] + bias[gc];
            }
}

// ---------------- flash attention: swapped-QK^T 32x32, lane-local softmax ----
// 512 blocks x 256 thr (4 waves, 32 q-rows each => 128 rows/block).
// mfma32(A,B): D[r][c] = sum_k A[r][k]*B[c][k]; C/D: col=lane&31,
// row = crow(r,hi) = (r&3)+8*(r>>2)+4*hi (m74/m101-verified); A/B-frag:
// row/col=lane&31, k = hi*8+j (any consistent k-map cancels in both MFMAs).
// S^T = mfma(K,Q): lane q=lane&31 holds P-row halves (kv split with lane^32
// partner).  O^T = mfma(V^T,P).  No LDS, no barriers.  Q pre-scaled by 1/8.
__global__ __launch_bounds__(256, 2) void attn_kernel(const unsigned short* __restrict__ Q,
                                                      const unsigned short* __restrict__ Kb,
                                                      const unsigned short* __restrict__ Vt,
                                                      unsigned short* __restrict__ Y) {
    const int tid = threadIdx.x, lane = tid & 63, w = tid >> 6;
    const int l31 = lane & 31, hi = lane >> 5;

    // XCD-chunked swizzle: same-(b,h) blocks share one XCD's L2; within a
    // head, pair long/short q-chunks so co-resident blocks balance.
    const int bid = blockIdx.x;
    const int wg  = (bid & 7) * 64 + (bid >> 3);
    const int bh  = wg >> 4;
    const int i16 = wg & 15;
    const int qch = (i16 & 1) ? (15 - (i16 >> 1)) : (i16 >> 1);
    const int qw  = qch * 128 + w * 32;            // wave's first q row

    const unsigned short* Qh = Q  + (size_t)bh * 2048 * 64;
    const unsigned short* Kh = Kb + (size_t)bh * 2048 * 64;
    const unsigned short* Vh = Vt + (size_t)bh * 64 * 2048;

    // Q B-frags (col q = qw+l31), 4 k-chunks of 16 over Dh=64
    bf16x8 qf[4];
#pragma unroll
    for (int c = 0; c < 4; ++c)
        qf[c] = *reinterpret_cast<const bf16x8*>(Qh + (size_t)(qw + l31) * 64 + c * 16 + hi * 8);

    f32x16 o0, o1;                      // O^T: d = crow(r,hi) + 32*dblk, col q
#pragma unroll
    for (int r = 0; r < 16; ++r) { o0[r] = 0.0f; o1[r] = 0.0f; }
    float mrun = -INFINITY, lrun = 0.0f;   // per-lane scalars (one q per lane)

    const int qg   = qw + l31;          // this lane's q row
    const int kend = qw + 31;           // last kv needed by this wave

    union UB { unsigned u[4]; bf16x8 v; };
    // Build PV B-frag words for one 16-kv chunk from SV[base..base+7].
    // Ownership (crow): hi=0 owns kv {0..3, 8..11}(+chunk), hi=1 {4..7,12..15}.
    // Need: hi=0 words = kv(01,23,45,67); hi=1 words = kv(89,10-11,12-13,14-15).
    // Exchange via __shfl_xor lane^32 (verified primitive).
#define PACK_HALF(SV, base, OUT) {                                        \
        unsigned lo01 = pack2(SV[(base) + 0], SV[(base) + 1]);            \
        unsigned lo23 = pack2(SV[(base) + 2], SV[(base) + 3]);            \
        unsigned hi01 = pack2(SV[(base) + 4], SV[(base) + 5]);            \
        unsigned hi23 = pack2(SV[(base) + 6], SV[(base) + 7]);            \
        unsigned s01  = hi ? lo01 : hi01;   /* what partner needs */      \
        unsigned s23  = hi ? lo23 : hi23;                                 \
        unsigned r01  = __shfl_xor(s01, 32, 64);                          \
        unsigned r23  = __shfl_xor(s23, 32, 64);                          \
        OUT.u[0] = hi ? r01  : lo01;                                      \
        OUT.u[1] = hi ? r23  : lo23;                                      \
        OUT.u[2] = hi ? hi01 : r01;                                       \
        OUT.u[3] = hi ? hi23 : r23; }

    for (int kb = 0; kb <= kend; kb += 64) {
        const bool act1 = (kb + 32 <= kend);    // wave-uniform

        // ---- issue all loads up front (16B/lane, L2-resident) ----
        bf16x8 kf0[4], kf1[4], vf0[4], vf1[4];
#pragma unroll
        for (int c = 0; c < 4; ++c)
            kf0[c] = *reinterpret_cast<const bf16x8*>(
                Kh + (size_t)(kb + l31) * 64 + c * 16 + hi * 8);
        if (act1) {
#pragma unroll
            for (int c = 0; c < 4; ++c)
                kf1[c] = *reinterpret_cast<const bf16x8*>(
                    Kh + (size_t)(kb + 32 + l31) * 64 + c * 16 + hi * 8);
        }
#pragma unroll
        for (int c = 0; c < 4; ++c) {
            vf0[c] = *reinterpret_cast<const bf16x8*>(
                Vh + (size_t)l31 * 2048 + kb + c * 16 + hi * 8);
            vf1[c] = *reinterpret_cast<const bf16x8*>(
                Vh + (size_t)(32 + l31) * 2048 + kb + c * 16 + hi * 8);
        }

        // ---- S^T = mfma(K, Q): two 32-kv tiles ----
        f32x16 s0, s1;
#pragma unroll
        for (int r = 0; r < 16; ++r) { s0[r] = 0.0f; s1[r] = 0.0f; }
#pragma unroll
        for (int c = 0; c < 4; ++c) s0 = MFMA32(kf0[c], qf[c], s0);
        if (act1) {
#pragma unroll
            for (int c = 0; c < 4; ++c) s1 = MFMA32(kf1[c], qf[c], s1);
        }

        // ---- causal mask (also kills inactive tile1: all lanes masked) ----
        if (kb + 31 > qw) {
#pragma unroll
            for (int r = 0; r < 16; ++r) {
                const int kv = kb + (r & 3) + 8 * (r >> 2) + 4 * hi;
                s0[r] = (kv > qg) ? -INFINITY : s0[r];
            }
        }
        if (kb + 63 > qw) {
#pragma unroll
            for (int r = 0; r < 16; ++r) {
                const int kv = kb + 32 + (r & 3) + 8 * (r >> 2) + 4 * hi;
                s1[r] = (kv > qg) ? -INFINITY : s1[r];
            }
        }

        // ---- lane-local online softmax (cross-half via shfl_xor 32) ----
        float t8[8];
#pragma unroll
        for (int r = 0; r < 8; ++r)
            t8[r] = fmaxf(fmaxf(s0[r], s0[r + 8]), fmaxf(s1[r], s1[r + 8]));
        float tm = fmaxf(fmaxf(fmaxf(t8[0], t8[1]), fmaxf(t8[2], t8[3])),
                         fmaxf(fmaxf(t8[4], t8[5]), fmaxf(t8[6], t8[7])));
        tm = fmaxf(tm, __shfl_xor(tm, 32, 64));
        const float mnew = fmaxf(mrun, tm);
        const float al = __expf(mrun - mnew);
        mrun = mnew;

#pragma unroll
        for (int r = 0; r < 16; ++r) {
            s0[r] = __expf(s0[r] - mnew);   // -inf -> 0
            s1[r] = __expf(s1[r] - mnew);
        }

        float u8[8];
#pragma unroll
        for (int r = 0; r < 8; ++r)
            u8[r] = (s0[r] + s0[r + 8]) + (s1[r] + s1[r + 8]);
        float us = ((u8[0] + u8[1]) + (u8[2] + u8[3])) + ((u8[4] + u8[5]) + (u8[6] + u8[7]));
        us += __shfl_xor(us, 32, 64);
        lrun = lrun * al + us;

#pragma unroll
        for (int r = 0; r < 16; ++r) { o0[r] *= al; o1[r] *= al; }

        // ---- P -> bf16 B-frags (pack + lane^32 exchange) ----
        UB p0, p1, p2, p3;                 // kv chunks kb+0..15, 16..31, 32..47, 48..63
        PACK_HALF(s0, 0, p0); PACK_HALF(s0, 8, p1);
        PACK_HALF(s1, 0, p2); PACK_HALF(s1, 8, p3);

        // ---- O^T += mfma(V^T, P) ----
        o0 = MFMA32(vf0[0], p0.v, o0);
        o0 = MFMA32(vf0[1], p1.v, o0);
        o0 = MFMA32(vf0[2], p2.v, o0);
        o0 = MFMA32(vf0[3], p3.v, o0);
        o1 = MFMA32(vf1[0], p0.v, o1);
        o1 = MFMA32(vf1[1], p1.v, o1);
        o1 = MFMA32(vf1[2], p2.v, o1);
        o1 = MFMA32(vf1[3], p3.v, o1);
    }
#undef PACK_HALF

    // ---- epilogue: y = O^T / l -> Y[(b, t, h*64+d)] ----
    const float inv = 1.0f / lrun;
    const int bb = bh >> 4, hh = bh & 15;
    unsigned short* Yrow = Y + ((size_t)(bb * 2048 + qg)) * 1024 + hh * 64;
#pragma unroll
    for (int r = 0; r < 16; ++r) {
        const int d = (r & 3) + 8 * (r >> 2) + 4 * hi;
        Yrow[d]      = f2bf(o0[r] * inv);
        Yrow[32 + d] = f2bf(o1[r] * inv);
    }
}

// ---------------------------------------------------------------------------
extern "C" void kernel_launch(void* const* d_in, const int* in_sizes, int n_in,
                              void* d_out, int out_size, void* d_ws, size_t ws_size,
                              hipStream_t stream) {
    (void)in_sizes; (void)n_in; (void)out_size; (void)ws_size;
    const float* x     = (const float*)d_in[0];
    const float* w_qkv = (const float*)d_in[1];
    const float* w_out = (const float*)d_in[2];
    const float* b_out = (const float*)d_in[3];
    float* out = (float*)d_out;

    // Workspace (bf16 elems), 41 MiB total. Yb aliases xb (x dead after GEMM1).
    unsigned short* xb    = (unsigned short*)d_ws;                    // 4096x1024
    unsigned short* Yb    = xb;                                       // alias
    unsigned short* wqkvb = xb    + (size_t)4096 * 1024;              // 3072x1024
    unsigned short* woutb = wqkvb + (size_t)3072 * 1024;              // 1024x1024
    unsigned short* Qb    = woutb + (size_t)1024 * 1024;              // 32x2048x64
    unsigned short* Kbuf  = Qb    + (size_t)32 * 2048 * 64;           // 32x2048x64
    unsigned short* Vt    = Kbuf  + (size_t)32 * 2048 * 64;           // 32x64x2048

    const int na4 = 4096 * 1024 / 4, nb4 = 3072 * 1024 / 4, nc4 = 1024 * 1024 / 4;
    cvt3_kernel<<<2048, 256, 0, stream>>>(x, w_qkv, w_out, xb, na4, nb4, na4 + nb4 + nc4);
    gemm_qkv_kernel<<<dim3(24, 32), 256, 0, stream>>>(xb, wqkvb, Qb, Kbuf, Vt);
    attn_kernel<<<512, 256, 0, stream>>>(Qb, Kbuf, Vt, Yb);
    gemm_out_kernel<<<dim3(8, 32), 256, 0, stream>>>(Yb, woutb, b_out, out);
}